// Round 6
// baseline (1050.388 us; speedup 1.0000x reference)
//
#include <hip/hip_runtime.h>

// Soft-Blake2 cipher: 2e6 rows x 16 f32 -> 2e6 x 8 f32.
// R5: packed fp32 (2 rows/thread, v_pk_* VOP3P). Trans-pipe attack:
//  - v_rcp_f32 + NR  ->  integer bit-trick estimate + 3 residual-NR (pk fma).
//    Removes 2 of 4 trans ops per sigmoid-pair (trans is 1/8-rate: 16 cyc
//    per wave64; the pair of rcp was 32 cyc, replacement is ~16 cyc full-rate).
//  - rint via magic-constant add: bit-identical n / f / scale (RNE; the
//    (as_int(tm)<<23)+0x3F800000 identity holds since 0x4B400000&0x1FF==0).
// exp path (v_exp_f32 on |f|<=0.5 + exact pow2 scale) is UNTOUCHED — it is
// the accuracy anchor (R3 showed ~1 ulp exp error => 2.5x absmax blowup).

#pragma clang fp contract(off)  // mul/add must round separately, like numpy

typedef float v2f __attribute__((ext_vector_type(2)));

// IV = float32(uint64) * 2^-64, matching np.asarray(ints, float32)/2.0**64.
#define IV0 ((float)7640891576956012808ULL * 0x1p-64f)
#define IV1 ((float)13503953896175478587ULL * 0x1p-64f)
#define IV2 ((float)4354685564936845355ULL * 0x1p-64f)
#define IV3 ((float)11912009170470909681ULL * 0x1p-64f)
#define IV4 ((float)5840696475078001361ULL * 0x1p-64f)
#define IV5 ((float)11170449401992604703ULL * 0x1p-64f)
#define IV6 ((float)2270897969802886507ULL * 0x1p-64f)
#define IV7 ((float)6620516959819538809ULL * 0x1p-64f)

// log2(e) split: HI = float(log2 e), LO = log2(e) - (double)HI.
#define L2E_HI 0x1.715476p+0f
#define L2E_LO 1.9259630e-8f
#define RMAGIC 0x1.8p23f  // round-to-int magic (RNE) for |t| < 2^22

static __device__ __forceinline__ v2f sp(float x) { return (v2f){x, x}; }
static __device__ __forceinline__ v2f vfma(v2f a, v2f b, v2f c) {
    return __builtin_elementwise_fma(a, b, c);
}
static __device__ __forceinline__ v2f vfloor(v2f a) {
    return __builtin_elementwise_floor(a);
}

// sigmoid(z) = 1/(1+e^-z), |z| <= ~35.
// n/f/scale/d bits identical to the R2/R4 passing path (proofs in header).
// Reciprocal: r0 = as_float(0x7EF311C3 - as_int(d)) (~5% rel err), then 3
// residual-form Newton steps -> ~0.5 ulp, converged to the same neighborhood
// as the old v_rcp+NR result.
static __device__ __forceinline__ v2f sigf2(v2f z) {
    v2f w = -z;
    v2f t = w * L2E_HI;                  // pk_mul
    v2f tm = t + sp(RMAGIC);             // pk_add: RNE round-to-int in mantissa
    v2f n = tm - sp(RMAGIC);             // pk_sub: n = rint(t), exact
    v2f f = vfma(w, sp(L2E_HI), -n);     // pk_fma (exact residual)
    f = vfma(w, sp(L2E_LO), f);          // pk_fma
    v2f e;
    e.x = __builtin_amdgcn_exp2f(f.x);   // 2x v_exp_f32 (only trans left)
    e.y = __builtin_amdgcn_exp2f(f.y);
    v2f sc;                              // 2^n exact: (n+127)<<23
    sc.x = __int_as_float((int)(((unsigned)__float_as_int(tm.x) << 23) + 0x3F800000u));
    sc.y = __int_as_float((int)(((unsigned)__float_as_int(tm.y) << 23) + 0x3F800000u));
    v2f d = vfma(e, sc, sp(1.0f));       // pk_fma, one rounding
    v2f r;                               // reciprocal bit-trick estimate
    r.x = __int_as_float(0x7EF311C3 - __float_as_int(d.x));
    r.y = __int_as_float(0x7EF311C3 - __float_as_int(d.y));
    v2f err = vfma(-d, r, sp(1.0f));     // NR1
    r = vfma(r, err, r);
    err = vfma(-d, r, sp(1.0f));         // NR2
    r = vfma(r, err, r);
    err = vfma(-d, r, sp(1.0f));         // NR3
    r = vfma(r, err, r);
    return r;
}

static __device__ __forceinline__ v2f soft_add2(v2f x, v2f y) {
    v2f s = x + y;
    v2f w = sigf2(10.0f * (s - 1.0f));   // sub then mul, ref rounding order
    return s - w;
}

static __device__ __forceinline__ v2f soft_xor2(v2f x, v2f y) {
    v2f xs = sigf2(10.0f * (x - 0.5f));
    v2f ys = sigf2(10.0f * (y - 0.5f));
    v2f t1 = xs * (1.0f - ys);
    v2f t2 = (1.0f - xs) * ys;
    v2f r = (t1 + t2) - t1 * t2;         // contraction off: rounds like numpy
    r = __builtin_elementwise_max(r, sp(0.0f));
    r = __builtin_elementwise_min(r, sp(1.0f));
    return r;
}

// rotate_right, bit-identical to the reference mod-2^64 chain (exact pow2
// scales; fract exact; single rounding at the same mantissa position).
template <int N>
static __device__ __forceinline__ v2f rotr2(v2f x) {
    constexpr float SHL = (float)(1ULL << (64 - N));  // 2^(64-N), exact
    constexpr float SHR = 1.0f / (float)(1ULL << N);  // 2^-N, exact
    v2f c = x * SHL;               // exact
    v2f sl = c - vfloor(c);        // exact fract
    v2f s = vfma(x, sp(SHR), sl);  // x*SHR exact => fma == mul-then-add
    return s - vfloor(s);          // exact fract
}

#define GFUN(a, b, c, d, x, y)             \
    do {                                   \
        v##a = soft_add2(v##a, v##b);      \
        v##a = soft_add2(v##a, (x));       \
        v##d = soft_xor2(v##d, v##a);      \
        v##d = rotr2<32>(v##d);            \
        v##c = soft_add2(v##c, v##d);      \
        v##b = soft_xor2(v##b, v##c);      \
        v##b = rotr2<24>(v##b);            \
        v##a = soft_add2(v##a, v##b);      \
        v##a = soft_add2(v##a, (y));       \
        v##d = soft_xor2(v##d, v##a);      \
        v##d = rotr2<16>(v##d);            \
        v##c = soft_add2(v##c, v##d);      \
        v##b = soft_xor2(v##b, v##c);      \
        v##b = rotr2<63>(v##b);            \
    } while (0)

__global__ __launch_bounds__(256) void blake_soft_kernel(
    const float* __restrict__ msg, float* __restrict__ out, int batch) {
    int p = blockIdx.x * blockDim.x + threadIdx.x;
    int i0 = 2 * p;
    if (i0 >= batch) return;
    int i1 = (i0 + 1 < batch) ? i0 + 1 : i0;  // tail guard (batch is even)

    const float4* mp = reinterpret_cast<const float4*>(msg);
    const float4* ma = mp + (size_t)i0 * 4;
    const float4* mb = mp + (size_t)i1 * 4;
    float4 a0 = ma[0], a1 = ma[1], a2 = ma[2], a3 = ma[3];
    float4 b0 = mb[0], b1 = mb[1], b2 = mb[2], b3 = mb[3];

    v2f m0 = {a0.x, b0.x}, m1 = {a0.y, b0.y}, m2 = {a0.z, b0.z}, m3 = {a0.w, b0.w};
    v2f m4 = {a1.x, b1.x}, m5 = {a1.y, b1.y}, m6 = {a1.z, b1.z}, m7 = {a1.w, b1.w};
    v2f m8 = {a2.x, b2.x}, m9 = {a2.y, b2.y}, m10 = {a2.z, b2.z}, m11 = {a2.w, b2.w};
    v2f m12 = {a3.x, b3.x}, m13 = {a3.y, b3.y}, m14 = {a3.z, b3.z}, m15 = {a3.w, b3.w};

    v2f s0 = sp(IV0), s1 = sp(IV1), s2 = sp(IV2), s3 = sp(IV3);
    v2f s4 = sp(IV4), s5 = sp(IV5), s6 = sp(IV6), s7 = sp(IV7);

#pragma unroll 1  // rounds are serial; keep I-cache footprint small
    for (int r = 0; r < 10; ++r) {
        v2f v0 = s0, v1 = s1, v2 = s2, v3 = s3;
        v2f v4 = s4, v5 = s5, v6 = s6, v7 = s7;
        v2f v8 = sp(IV0), v9 = sp(IV1), v10 = sp(IV2), v11 = sp(IV3);
        v2f v12 = sp(IV4), v13 = sp(IV5), v14 = sp(IV6), v15 = sp(IV7);

        GFUN(0, 4, 8, 12, m0, m1);
        GFUN(1, 5, 9, 13, m2, m3);
        GFUN(2, 6, 10, 14, m4, m5);
        GFUN(3, 7, 11, 15, m6, m7);
        GFUN(0, 5, 10, 15, m8, m9);
        GFUN(1, 6, 11, 12, m10, m11);
        GFUN(2, 7, 8, 13, m12, m13);
        GFUN(3, 4, 9, 14, m14, m15);

        s0 = soft_xor2(v0, v8);
        s1 = soft_xor2(v1, v9);
        s2 = soft_xor2(v2, v10);
        s3 = soft_xor2(v3, v11);
        s4 = soft_xor2(v4, v12);
        s5 = soft_xor2(v5, v13);
        s6 = soft_xor2(v6, v14);
        s7 = soft_xor2(v7, v15);
    }

    float4* op = reinterpret_cast<float4*>(out);
    float4 oa0 = {s0.x, s1.x, s2.x, s3.x};
    float4 oa1 = {s4.x, s5.x, s6.x, s7.x};
    op[(size_t)i0 * 2 + 0] = oa0;
    op[(size_t)i0 * 2 + 1] = oa1;
    if (i1 != i0) {
        float4 ob0 = {s0.y, s1.y, s2.y, s3.y};
        float4 ob1 = {s4.y, s5.y, s6.y, s7.y};
        op[(size_t)i1 * 2 + 0] = ob0;
        op[(size_t)i1 * 2 + 1] = ob1;
    }
}

extern "C" void kernel_launch(void* const* d_in, const int* in_sizes, int n_in,
                              void* d_out, int out_size, void* d_ws, size_t ws_size,
                              hipStream_t stream) {
    (void)n_in;
    (void)out_size;
    (void)d_ws;
    (void)ws_size;
    const float* msg = (const float*)d_in[0];
    float* out = (float*)d_out;
    int batch = in_sizes[0] / 16;
    int pairs = (batch + 1) / 2;
    int block = 256;
    int grid = (pairs + block - 1) / block;
    blake_soft_kernel<<<grid, block, 0, stream>>>(msg, out, batch);
}